// Round 5
// baseline (200.226 us; speedup 1.0000x reference)
//
#include <hip/hip_runtime.h>

#define NN 64
#define CC 3
#define LL 4096
#define SS 64
#define KK 128
#define WW 4033           // LL - SS + 1
#define BLKN 8            // blocks per n (each covers 512 windows)

typedef __attribute__((ext_vector_type(8))) short v8s;   // 8 bf16 MFMA A/B frag
typedef __attribute__((ext_vector_type(4))) float v4f;   // 4 fp32 MFMA C/D frag

// ---- ws layout (bytes) ----
// d2g:  u32[NN*KK]        @ 0       (32768)
// cnt:  u32[NN]           @ 32768   (256)
// hs2g: f32[CC*KK]        @ 33024   (1536)   -0.5*||s||^2
// shb:  uint4[CC*1024]    @ 34560   (49152)  fragment-order bf16 shapelets
#define WS_CNT_OFF 32768
#define WS_HS2_OFF 33024
#define WS_SHB_OFF 34560

__device__ __forceinline__ unsigned bf16_rne(float f) {
    unsigned u = __float_as_uint(f);
    return (u + 0x7FFFu + ((u >> 16) & 1u)) >> 16;
}

// ---------------------------------------------------------------------------
// Tiny prep (identical to the passing round-2 version): 32 blocks x 256.
// Inits d2g/cnt, computes -0.5*||s||^2, packs bf16 shapelet fragments.
__global__ __launch_bounds__(256) void me_prep(
        const float* __restrict__ shp,
        unsigned* __restrict__ d2g,
        unsigned* __restrict__ cnt,
        float* __restrict__ hs2g,
        uint4* __restrict__ shb) {
    const int tid = blockIdx.x * 256 + threadIdx.x;
    d2g[tid] = 0x7F800000u;                    // +inf bits (all 8192)
    if (tid < NN) cnt[tid] = 0u;
    if (tid < CC * KK) {
        const float4* r4 = (const float4*)(shp + (size_t)tid * SS);
        float a = 0.f;
        #pragma unroll
        for (int i = 0; i < 16; ++i) {
            float4 v = r4[i];
            a += v.x * v.x + v.y * v.y + v.z * v.z + v.w * v.w;
        }
        hs2g[tid] = -0.5f * a;
    }
    if (tid < CC * 1024) {
        // B-operand frag order: chunk ((c*8+nt)*2+sc)*64+lane holds
        // shp[c][nt*16+(lane&15)][sc*32+(lane>>4)*8 + j], j=0..7 (RNE bf16)
        int c   = tid >> 10;
        int r   = tid & 1023;
        int nt  = r >> 7;
        int scb = (r >> 6) & 1;
        int l   = r & 63;
        int row  = nt * 16 + (l & 15);
        int koff = scb * 32 + (l >> 4) * 8;
        const float* s = shp + ((size_t)(c * KK + row)) * SS + koff;
        float4 f0 = *(const float4*)s;
        float4 f1 = *(const float4*)(s + 4);
        uint4 o;
        o.x = (bf16_rne(f0.y) << 16) | bf16_rne(f0.x);
        o.y = (bf16_rne(f0.w) << 16) | bf16_rne(f0.z);
        o.z = (bf16_rne(f1.y) << 16) | bf16_rne(f1.x);
        o.w = (bf16_rne(f1.w) << 16) | bf16_rne(f1.z);
        shb[tid] = o;
    }
}

// ---------------------------------------------------------------------------
// Main: 512 blocks = (n, 512-window group) -- round-2 decomposition and
// finish protocol (validated by the tripwire twice). Block-internal changes
// only: in-register scan writes hx directly (no Ps buffer, 2 pipeline
// barriers instead of 4) and iteration-1 global loads are issued before
// compute(0) so HBM latency hides under MFMA. Finish hardened with
// __threadfence release/acquire around the d2g -> cnt handoff.
__global__ __launch_bounds__(256, 2) void me_main(
        const float* __restrict__ x,
        const ushort* __restrict__ shb_g,
        const float* __restrict__ hs2g,
        unsigned* __restrict__ d2g,
        unsigned* __restrict__ cnt,
        float* __restrict__ out) {

    __shared__ __align__(16) ushort shb[CC * 8192];   // 48 KB shapelet frags
    __shared__ __align__(8) ushort xs2[2][2][CC][320];// [buf][copy][c] bf16 x
    __shared__ __align__(16) float hx[2][CC][256];    // [buf] -0.5*sliding x2
    __shared__ unsigned red[KK];
    __shared__ int lastflag;

    const int b    = blockIdx.x;
    const int n    = b >> 3;          // BLKN=8 blocks per n
    const int tg   = b & 7;
    const int t    = threadIdx.x;
    const int lane = t & 63, wave = t >> 6;
    const int quad = lane >> 4, col = lane & 15;
    const int wbase = wave * 64;      // wave's window base within supertile

    if (t < KK) red[t] = 0x7F800000u;

    // ---- DMA all shapelet frags global(ws) -> LDS, once per block ----
    {
        typedef __attribute__((address_space(1))) const uint4 gu4;
        typedef __attribute__((address_space(3))) uint4 lu4;
        const uint4* gbase = (const uint4*)shb_g;
        #pragma unroll
        for (int it = 0; it < 12; ++it) {
            const uint4* gp = gbase + it * 256 + t;                 // per-lane
            uint4* lp = (uint4*)shb + (it * 256 + wave * 64);       // wave-uniform
            __builtin_amdgcn_global_load_lds((gu4*)gp, (lu4*)lp, 16, 0, 0);
        }
    }

    // ---- -0.5*s2 into registers (indexed by this lane's col) ----
    float hsv[CC][8];
    #pragma unroll
    for (int c = 0; c < CC; ++c)
        #pragma unroll
        for (int nt = 0; nt < 8; ++nt)
            hsv[c][nt] = hs2g[c * KK + nt * 16 + col];

    const float* xb = x + (size_t)n * (CC * LL);

    // staging role: t<240 covers 3 channels x 80 threads x 4 elems
    const bool do_stage = (t < 240);
    const int  cs   = t / 80;              // staging channel
    const int  sidx = (t - cs * 80) * 4;   // element base within 320

    float4 stv;          // staged x (4 elems, channel cs)
    float  qq[5];        // scan regs (channel = wave, waves 0..2)

    // ---- load(it): issue global loads into regs (no dependent ALU) ----
    auto load_xt = [&](int it) {
        const int w0 = tg * 512 + it * 256;
        if (do_stage) {
            int gi = w0 + sidx;
            const float* xc = xb + cs * LL;
            if (gi + 3 < LL) stv = *(const float4*)(xc + gi);
            else {
                stv.x = (gi     < LL) ? xc[gi]     : 0.f;
                stv.y = (gi + 1 < LL) ? xc[gi + 1] : 0.f;
                stv.z = (gi + 2 < LL) ? xc[gi + 2] : 0.f;
                stv.w = (gi + 3 < LL) ? xc[gi + 3] : 0.f;
            }
        }
        if (wave < CC) {
            const float* xp = xb + wave * LL + w0;
            #pragma unroll
            for (int i = 0; i < 5; ++i) {
                int idx = lane * 5 + i;
                qq[i] = (w0 + idx < LL) ? xp[idx] : 0.f;
            }
        }
    };

    // ---- consume(it): bf16 dual-copy store + in-register scan -> hx ----
    auto store_xt = [&](int it) {
        const int w0 = tg * 512 + it * 256;
        if (do_stage) {
            unsigned h0 = bf16_rne(stv.x), h1 = bf16_rne(stv.y);
            unsigned h2 = bf16_rne(stv.z), h3 = bf16_rne(stv.w);
            uint2 p0; p0.x = h0 | (h1 << 16); p0.y = h2 | (h3 << 16);
            *(uint2*)&xs2[it][0][cs][sidx] = p0;                  // copy0: x[i]
            if (sidx > 0) xs2[it][1][cs][sidx - 1] = (ushort)h0;  // copy1: x[i+1]
            *(uint*)&xs2[it][1][cs][sidx] = h1 | (h2 << 16);
            xs2[it][1][cs][sidx + 2] = (ushort)h3;
        }
        if (wave < CC) {
            // inclusive prefix of x^2 over 320 elems (5/lane)
            float p[5]; float runv = 0.f;
            #pragma unroll
            for (int i = 0; i < 5; ++i) { runv += qq[i] * qq[i]; p[i] = runv; }
            float scv = runv;
            #pragma unroll
            for (int d = 1; d < 64; d <<= 1) {
                float u = __shfl_up(scv, d, 64);
                if (lane >= d) scv += u;
            }
            float excl = scv - runv;
            #pragma unroll
            for (int i = 0; i < 5; ++i) p[i] += excl;
            // hx[w] = -0.5*(P[w+63]-P[w-1]); w = 5*lane+i
            // P[w+63]: i<2 -> lane+12 elem i+3; i>=2 -> lane+13 elem i-2
            float hi0 = __shfl_down(p[3], 12, 64);
            float hi1 = __shfl_down(p[4], 12, 64);
            float hi2 = __shfl_down(p[0], 13, 64);
            float hi3 = __shfl_down(p[1], 13, 64);
            float hi4 = __shfl_down(p[2], 13, 64);
            float up4 = __shfl_up(p[4], 1, 64);
            float hi[5] = {hi0, hi1, hi2, hi3, hi4};
            float lo[5];
            lo[0] = (lane == 0) ? 0.f : up4;
            lo[1] = p[0]; lo[2] = p[1]; lo[3] = p[2]; lo[4] = p[3];
            int wb = lane * 5;
            if (wb < 256) {                       // lanes 0..51
                #pragma unroll
                for (int i = 0; i < 5; ++i) {
                    int w = wb + i;
                    if (w < 256) {
                        float o = -0.5f * (hi[i] - lo[i]);
                        if (w0 + w >= WW) o = -1e30f;   // pad windows masked
                        hx[it][wave][w] = o;
                    }
                }
            }
        }
    };

    float rmax[8];
    #pragma unroll
    for (int nt = 0; nt < 8; ++nt) rmax[nt] = -3.4e38f;

    // ---- compute(it): MFMA supertile over 3 channels, epilogue max-fold ----
    auto compute = [&](int it) {
        #pragma unroll
        for (int c = 0; c < CC; ++c) {
            // -0.5*x2 for this wave's 64 window rows (LDS, quad-broadcast)
            v4f hxv[4];
            #pragma unroll
            for (int mt = 0; mt < 4; ++mt)
                hxv[mt] = *(const v4f*)&hx[it][c][wbase + mt * 16 + quad * 4];
            // A-frags: 4 m-tiles x 2 k-chunks, dual-copy dword-aligned reads
            v8s af[4][2];
            #pragma unroll
            for (int mt = 0; mt < 4; ++mt)
                #pragma unroll
                for (int sc = 0; sc < 2; ++sc) {
                    int e0 = wbase + mt * 16 + col + sc * 32 + quad * 8;
                    int pp = col & 1;
                    const uint* ap = (const uint*)&xs2[it][pp][c][e0 - pp];
                    union { v8s v; uint u[4]; } au;
                    au.u[0] = ap[0]; au.u[1] = ap[1];
                    au.u[2] = ap[2]; au.u[3] = ap[3];
                    af[mt][sc] = au.v;
                }
            // two groups of 4 n-tiles to bound acc register pressure
            #pragma unroll
            for (int g = 0; g < 2; ++g) {
                v4f acc[4][4];   // [nt2][mt]
                #pragma unroll
                for (int nt2 = 0; nt2 < 4; ++nt2) {
                    float h = hsv[c][g * 4 + nt2];
                    v4f a = {h, h, h, h};
                    #pragma unroll
                    for (int mt = 0; mt < 4; ++mt) acc[nt2][mt] = a;
                }
                #pragma unroll
                for (int sc = 0; sc < 2; ++sc)
                    #pragma unroll
                    for (int nt2 = 0; nt2 < 4; ++nt2) {
                        int nt = g * 4 + nt2;
                        v8s bfr = *(const v8s*)(shb + (((c * 8 + nt) * 2 + sc) * 64 + lane) * 8);
                        #pragma unroll
                        for (int mt = 0; mt < 4; ++mt)
                            acc[nt2][mt] = __builtin_amdgcn_mfma_f32_16x16x32_bf16(
                                af[mt][sc], bfr, acc[nt2][mt], 0, 0, 0);
                    }
                // epilogue: add -0.5*x2 rows, fold max over 16 window rows
                #pragma unroll
                for (int nt2 = 0; nt2 < 4; ++nt2) {
                    float m = -3.4e38f;
                    #pragma unroll
                    for (int mt = 0; mt < 4; ++mt) {
                        v4f a = acc[nt2][mt];
                        #pragma unroll
                        for (int r = 0; r < 4; ++r)
                            m = fmaxf(m, a[r] + hxv[mt][r]);
                    }
                    rmax[g * 4 + nt2] = fmaxf(rmax[g * 4 + nt2], m);
                }
            }
        }
    };

    // ---- pipelined schedule: 2 barriers ----
    load_xt(0);
    store_xt(0);
    __syncthreads();      // xs2[0]/hx[0] ready; drains shapelet DMA (vmcnt 0)
    load_xt(1);           // it1 global loads in flight under compute(0)
    compute(0);
    store_xt(1);
    __syncthreads();      // xs2[1]/hx[1] ready
    compute(1);

    // ---- reduce over quads (window rows live across quad+regs) ----
    #pragma unroll
    for (int nt = 0; nt < 8; ++nt) {
        float v = rmax[nt];
        v = fmaxf(v, __shfl_xor(v, 16, 64));
        v = fmaxf(v, __shfl_xor(v, 32, 64));
        rmax[nt] = v;
    }
    if (quad == 0) {
        #pragma unroll
        for (int nt = 0; nt < 8; ++nt) {
            float d2 = fmaxf(-2.f * rmax[nt], 0.f);
            atomicMin(&red[nt * 16 + col], __float_as_uint(d2));
        }
    }
    __syncthreads();
    if (t < KK) atomicMin(&d2g[n * KK + t], red[t]);   // device-scope RMW
    __threadfence();   // release: this block's d2g mins visible device-wide
    __syncthreads();
    if (t == 0) {
        unsigned old = atomicAdd(&cnt[n], 1u);
        lastflag = (old == BLKN - 1) ? 1 : 0;
    }
    __syncthreads();
    __threadfence();   // acquire: see all blocks' d2g mins after cnt == BLKN
    if (lastflag && t < KK) {
        unsigned bits = atomicMin(&d2g[n * KK + t], 0x7F800000u);
        out[n * KK + t] = sqrtf(__uint_as_float(bits));
    }
}

// ---------------------------------------------------------------------------
extern "C" void kernel_launch(void* const* d_in, const int* in_sizes, int n_in,
                              void* d_out, int out_size, void* d_ws, size_t ws_size,
                              hipStream_t stream) {
    const float* x   = (const float*)d_in[0];   // (N, C, L) fp32
    const float* shp = (const float*)d_in[1];   // (C, K, S) fp32
    unsigned* d2g  = (unsigned*)d_ws;
    unsigned* cnt  = (unsigned*)((char*)d_ws + WS_CNT_OFF);
    float*    hs2g = (float*)((char*)d_ws + WS_HS2_OFF);
    uint4*    shb  = (uint4*)((char*)d_ws + WS_SHB_OFF);
    float* out = (float*)d_out;

    hipLaunchKernelGGL(me_prep, dim3(32), dim3(256), 0, stream,
                       shp, d2g, cnt, hs2g, shb);
    hipLaunchKernelGGL(me_main, dim3(NN * BLKN), dim3(256), 0, stream,
                       x, (const ushort*)shb, hs2g, d2g, cnt, out);
}

// Round 6
// 127.061 us; speedup vs baseline: 1.5758x; 1.5758x over previous
//
#include <hip/hip_runtime.h>

#define NN 64
#define CC 3
#define LL 4096
#define SS 64
#define KK 128
#define WW 4033           // LL - SS + 1
#define BLKN 8            // blocks per n (each covers 512 windows)

typedef __attribute__((ext_vector_type(8))) short v8s;   // 8 bf16 MFMA A/B frag
typedef __attribute__((ext_vector_type(4))) float v4f;   // 4 fp32 MFMA C/D frag

// ---- ws layout (bytes) ----
// d2g:  u32[NN*KK]        @ 0       (32768)
// cnt:  u32[NN]           @ 32768   (256)
// hs2g: f32[CC*KK]        @ 33024   (1536)   -0.5*||s||^2
// shb:  uint4[CC*1024]    @ 34560   (49152)  fragment-order bf16 shapelets
#define WS_CNT_OFF 32768
#define WS_HS2_OFF 33024
#define WS_SHB_OFF 34560

__device__ __forceinline__ unsigned bf16_rne(float f) {
    unsigned u = __float_as_uint(f);
    return (u + 0x7FFFu + ((u >> 16) & 1u)) >> 16;
}

// ---------------------------------------------------------------------------
// Tiny prep (identical to the passing round-2 version): 32 blocks x 256.
// Inits d2g/cnt, computes -0.5*||s||^2, packs bf16 shapelet fragments.
__global__ __launch_bounds__(256) void me_prep(
        const float* __restrict__ shp,
        unsigned* __restrict__ d2g,
        unsigned* __restrict__ cnt,
        float* __restrict__ hs2g,
        uint4* __restrict__ shb) {
    const int tid = blockIdx.x * 256 + threadIdx.x;
    d2g[tid] = 0x7F800000u;                    // +inf bits (all 8192)
    if (tid < NN) cnt[tid] = 0u;
    if (tid < CC * KK) {
        const float4* r4 = (const float4*)(shp + (size_t)tid * SS);
        float a = 0.f;
        #pragma unroll
        for (int i = 0; i < 16; ++i) {
            float4 v = r4[i];
            a += v.x * v.x + v.y * v.y + v.z * v.z + v.w * v.w;
        }
        hs2g[tid] = -0.5f * a;
    }
    if (tid < CC * 1024) {
        // B-operand frag order: chunk ((c*8+nt)*2+sc)*64+lane holds
        // shp[c][nt*16+(lane&15)][sc*32+(lane>>4)*8 + j], j=0..7 (RNE bf16)
        int c   = tid >> 10;
        int r   = tid & 1023;
        int nt  = r >> 7;
        int scb = (r >> 6) & 1;
        int l   = r & 63;
        int row  = nt * 16 + (l & 15);
        int koff = scb * 32 + (l >> 4) * 8;
        const float* s = shp + ((size_t)(c * KK + row)) * SS + koff;
        float4 f0 = *(const float4*)s;
        float4 f1 = *(const float4*)(s + 4);
        uint4 o;
        o.x = (bf16_rne(f0.y) << 16) | bf16_rne(f0.x);
        o.y = (bf16_rne(f0.w) << 16) | bf16_rne(f0.z);
        o.z = (bf16_rne(f1.y) << 16) | bf16_rne(f1.x);
        o.w = (bf16_rne(f1.w) << 16) | bf16_rne(f1.z);
        shb[tid] = o;
    }
}

// ---------------------------------------------------------------------------
// Main: 512 blocks = (n, 512-window group). Round-2 structure and finish
// protocol (tripwire-validated), straight-line code (no lambdas -- r5's
// lambda rewrite forced captures to scratch: 290 MB HBM traffic, 7x slow).
// Single delta vs round 2: the x^2 prefix scan stays in registers and
// writes hx directly (no Ps buffer), cutting barriers to 1 per iteration.
// hx is dual-buffered so no trailing barrier is needed.
__global__ __launch_bounds__(256, 2) void me_main(
        const float* __restrict__ x,
        const ushort* __restrict__ shb_g,
        const float* __restrict__ hs2g,
        unsigned* __restrict__ d2g,
        unsigned* __restrict__ cnt,
        float* __restrict__ out) {

    __shared__ __align__(16) ushort shb[CC * 8192];   // 48 KB shapelet frags
    __shared__ __align__(8) ushort xs2[2][2][CC][320];// [buf][copy][c] bf16 x
    __shared__ __align__(16) float hx[2][CC][256];    // [buf] -0.5*sliding x2
    __shared__ unsigned red[KK];
    __shared__ int lastflag;

    const int b    = blockIdx.x;
    const int n    = b >> 3;          // BLKN=8 blocks per n
    const int tg   = b & 7;
    const int t    = threadIdx.x;
    const int lane = t & 63, wave = t >> 6;
    const int quad = lane >> 4, col = lane & 15;
    const int wbase = wave * 64;      // wave's window base within supertile

    if (t < KK) red[t] = 0x7F800000u;

    // ---- DMA all shapelet frags global(ws) -> LDS, once per block ----
    {
        typedef __attribute__((address_space(1))) const uint4 gu4;
        typedef __attribute__((address_space(3))) uint4 lu4;
        const uint4* gbase = (const uint4*)shb_g;
        #pragma unroll
        for (int it = 0; it < 12; ++it) {
            const uint4* gp = gbase + it * 256 + t;                 // per-lane
            uint4* lp = (uint4*)shb + (it * 256 + wave * 64);       // wave-uniform
            __builtin_amdgcn_global_load_lds((gu4*)gp, (lu4*)lp, 16, 0, 0);
        }
    }

    // ---- -0.5*s2 into registers (indexed by this lane's col) ----
    float hsv[CC][8];
    #pragma unroll
    for (int c = 0; c < CC; ++c)
        #pragma unroll
        for (int nt = 0; nt < 8; ++nt)
            hsv[c][nt] = hs2g[c * KK + nt * 16 + col];

    const float* xb = x + (size_t)n * (CC * LL);

    float rmax[8];
    #pragma unroll
    for (int nt = 0; nt < 8; ++nt) rmax[nt] = -3.4e38f;

    for (int it = 0; it < 2; ++it) {
        const int buf = it;
        const int w0  = tg * 512 + it * 256;

        // ---- stage 256+63 x elems per channel, bf16 dual-copy ----
        if (t < 240) {
            int c = t / 80, q = t - c * 80;
            int idx = q * 4, gi = w0 + idx;
            float4 v;
            if (gi + 3 < LL) v = *(const float4*)(xb + c * LL + gi);
            else {
                v.x = (gi     < LL) ? xb[c * LL + gi]     : 0.f;
                v.y = (gi + 1 < LL) ? xb[c * LL + gi + 1] : 0.f;
                v.z = (gi + 2 < LL) ? xb[c * LL + gi + 2] : 0.f;
                v.w = (gi + 3 < LL) ? xb[c * LL + gi + 3] : 0.f;
            }
            unsigned h0 = bf16_rne(v.x), h1 = bf16_rne(v.y);
            unsigned h2 = bf16_rne(v.z), h3 = bf16_rne(v.w);
            uint2 p0; p0.x = h0 | (h1 << 16); p0.y = h2 | (h3 << 16);
            *(uint2*)&xs2[buf][0][c][idx] = p0;                 // copy0: x[i]
            if (idx > 0) xs2[buf][1][c][idx - 1] = (ushort)h0;  // copy1: x[i+1]
            *(uint*)&xs2[buf][1][c][idx] = h1 | (h2 << 16);
            xs2[buf][1][c][idx + 2] = (ushort)h3;
        }
        // ---- in-register x^2 prefix scan -> hx, 1 wave per channel ----
        if (wave < CC) {
            const float* xp = xb + wave * LL + w0;
            float p[5]; float runv = 0.f;
            #pragma unroll
            for (int i = 0; i < 5; ++i) {
                int idx = lane * 5 + i;
                float v = (w0 + idx < LL) ? xp[idx] : 0.f;
                runv += v * v; p[i] = runv;
            }
            float scv = runv;
            #pragma unroll
            for (int d = 1; d < 64; d <<= 1) {
                float u = __shfl_up(scv, d, 64);
                if (lane >= d) scv += u;
            }
            float excl = scv - runv;
            #pragma unroll
            for (int i = 0; i < 5; ++i) p[i] += excl;
            // hx[w] = -0.5*(P[w+63]-P[w-1]); w = 5*lane+i
            // P[w+63]: i<2 -> lane+12 elem i+3; i>=2 -> lane+13 elem i-2
            float hi0 = __shfl_down(p[3], 12, 64);
            float hi1 = __shfl_down(p[4], 12, 64);
            float hi2 = __shfl_down(p[0], 13, 64);
            float hi3 = __shfl_down(p[1], 13, 64);
            float hi4 = __shfl_down(p[2], 13, 64);
            float up4 = __shfl_up(p[4], 1, 64);
            float hi[5] = {hi0, hi1, hi2, hi3, hi4};
            float lo[5];
            lo[0] = (lane == 0) ? 0.f : up4;
            lo[1] = p[0]; lo[2] = p[1]; lo[3] = p[2]; lo[4] = p[3];
            int wb = lane * 5;
            if (wb < 256) {                       // lanes 0..51
                #pragma unroll
                for (int i = 0; i < 5; ++i) {
                    int w = wb + i;
                    if (w < 256) {
                        float o = -0.5f * (hi[i] - lo[i]);
                        if (w0 + w >= WW) o = -1e30f;   // pad windows masked
                        hx[buf][wave][w] = o;
                    }
                }
            }
        }
        __syncthreads();   // one barrier per iteration (covers DMA on it==0)

        #pragma unroll
        for (int c = 0; c < CC; ++c) {
            // -0.5*x2 for this wave's 64 window rows (LDS, quad-broadcast)
            v4f hxv[4];
            #pragma unroll
            for (int mt = 0; mt < 4; ++mt)
                hxv[mt] = *(const v4f*)&hx[buf][c][wbase + mt * 16 + quad * 4];
            // A-frags: 4 m-tiles x 2 k-chunks, dual-copy dword-aligned reads
            v8s af[4][2];
            #pragma unroll
            for (int mt = 0; mt < 4; ++mt)
                #pragma unroll
                for (int sc = 0; sc < 2; ++sc) {
                    int e0 = wbase + mt * 16 + col + sc * 32 + quad * 8;
                    int p  = col & 1;
                    const uint* ap = (const uint*)&xs2[buf][p][c][e0 - p];
                    union { v8s v; uint u[4]; } au;
                    au.u[0] = ap[0]; au.u[1] = ap[1];
                    au.u[2] = ap[2]; au.u[3] = ap[3];
                    af[mt][sc] = au.v;
                }
            // two groups of 4 n-tiles to bound acc register pressure
            #pragma unroll
            for (int g = 0; g < 2; ++g) {
                v4f acc[4][4];   // [nt2][mt]
                #pragma unroll
                for (int nt2 = 0; nt2 < 4; ++nt2) {
                    float h = hsv[c][g * 4 + nt2];
                    v4f a = {h, h, h, h};
                    #pragma unroll
                    for (int mt = 0; mt < 4; ++mt) acc[nt2][mt] = a;
                }
                #pragma unroll
                for (int sc = 0; sc < 2; ++sc)
                    #pragma unroll
                    for (int nt2 = 0; nt2 < 4; ++nt2) {
                        int nt = g * 4 + nt2;
                        v8s bfr = *(const v8s*)(shb + (((c * 8 + nt) * 2 + sc) * 64 + lane) * 8);
                        #pragma unroll
                        for (int mt = 0; mt < 4; ++mt)
                            acc[nt2][mt] = __builtin_amdgcn_mfma_f32_16x16x32_bf16(
                                af[mt][sc], bfr, acc[nt2][mt], 0, 0, 0);
                    }
                // epilogue: add -0.5*x2 rows, fold max over 16 window rows
                #pragma unroll
                for (int nt2 = 0; nt2 < 4; ++nt2) {
                    float m = -3.4e38f;
                    #pragma unroll
                    for (int mt = 0; mt < 4; ++mt) {
                        v4f a = acc[nt2][mt];
                        #pragma unroll
                        for (int r = 0; r < 4; ++r)
                            m = fmaxf(m, a[r] + hxv[mt][r]);
                    }
                    rmax[g * 4 + nt2] = fmaxf(rmax[g * 4 + nt2], m);
                }
            }
        }
        // no trailing barrier: next iteration writes the other xs2/hx buffer;
        // all threads passed this iteration's barrier before any writer
        // touches buf^1, and compute reads only buf
    }

    // ---- reduce over quads (window rows live across quad+regs) ----
    #pragma unroll
    for (int nt = 0; nt < 8; ++nt) {
        float v = rmax[nt];
        v = fmaxf(v, __shfl_xor(v, 16, 64));
        v = fmaxf(v, __shfl_xor(v, 32, 64));
        rmax[nt] = v;
    }
    if (quad == 0) {
        #pragma unroll
        for (int nt = 0; nt < 8; ++nt) {
            float d2 = fmaxf(-2.f * rmax[nt], 0.f);
            atomicMin(&red[nt * 16 + col], __float_as_uint(d2));
        }
    }
    __syncthreads();
    if (t < KK) atomicMin(&d2g[n * KK + t], red[t]);   // device-scope RMW
    __threadfence();   // release: this block's d2g mins visible device-wide
    __syncthreads();
    if (t == 0) {
        unsigned old = atomicAdd(&cnt[n], 1u);
        lastflag = (old == BLKN - 1) ? 1 : 0;
    }
    __syncthreads();
    __threadfence();   // acquire: see all blocks' d2g mins after cnt == BLKN
    if (lastflag && t < KK) {
        unsigned bits = atomicMin(&d2g[n * KK + t], 0x7F800000u);
        out[n * KK + t] = sqrtf(__uint_as_float(bits));
    }
}

// ---------------------------------------------------------------------------
extern "C" void kernel_launch(void* const* d_in, const int* in_sizes, int n_in,
                              void* d_out, int out_size, void* d_ws, size_t ws_size,
                              hipStream_t stream) {
    const float* x   = (const float*)d_in[0];   // (N, C, L) fp32
    const float* shp = (const float*)d_in[1];   // (C, K, S) fp32
    unsigned* d2g  = (unsigned*)d_ws;
    unsigned* cnt  = (unsigned*)((char*)d_ws + WS_CNT_OFF);
    float*    hs2g = (float*)((char*)d_ws + WS_HS2_OFF);
    uint4*    shb  = (uint4*)((char*)d_ws + WS_SHB_OFF);
    float* out = (float*)d_out;

    hipLaunchKernelGGL(me_prep, dim3(32), dim3(256), 0, stream,
                       shp, d2g, cnt, hs2g, shb);
    hipLaunchKernelGGL(me_main, dim3(NN * BLKN), dim3(256), 0, stream,
                       x, (const ushort*)shb, hs2g, d2g, cnt, out);
}

// Round 7
// 73.220 us; speedup vs baseline: 2.7346x; 1.7353x over previous
//
#include <hip/hip_runtime.h>

#define NN 64
#define CC 3
#define LL 4096
#define SS 64
#define KK 128
#define WW 4033           // LL - SS + 1
#define BLKN 8            // blocks per n (each covers 512 windows)

typedef __attribute__((ext_vector_type(8))) short v8s;   // 8 bf16 MFMA A/B frag
typedef __attribute__((ext_vector_type(4))) float v4f;   // 4 fp32 MFMA C/D frag

// ---- ws layout (bytes) ----
// d2g:  u32[NN*KK]        @ 0       (32768)
// cnt:  u32[NN]           @ 32768   (256)
// hs2g: f32[CC*KK]        @ 33024   (1536)   -0.5*||s||^2
// shb:  uint4[CC*1024]    @ 34560   (49152)  fragment-order bf16 shapelets
#define WS_CNT_OFF 32768
#define WS_HS2_OFF 33024
#define WS_SHB_OFF 34560

__device__ __forceinline__ unsigned bf16_rne(float f) {
    unsigned u = __float_as_uint(f);
    return (u + 0x7FFFu + ((u >> 16) & 1u)) >> 16;
}

// ---------------------------------------------------------------------------
// Tiny prep (identical to the passing round-2 version): 32 blocks x 256.
// Inits d2g/cnt, computes -0.5*||s||^2, packs bf16 shapelet fragments.
__global__ __launch_bounds__(256) void me_prep(
        const float* __restrict__ shp,
        unsigned* __restrict__ d2g,
        unsigned* __restrict__ cnt,
        float* __restrict__ hs2g,
        uint4* __restrict__ shb) {
    const int tid = blockIdx.x * 256 + threadIdx.x;
    d2g[tid] = 0x7F800000u;                    // +inf bits (all 8192)
    if (tid < NN) cnt[tid] = 0u;
    if (tid < CC * KK) {
        const float4* r4 = (const float4*)(shp + (size_t)tid * SS);
        float a = 0.f;
        #pragma unroll
        for (int i = 0; i < 16; ++i) {
            float4 v = r4[i];
            a += v.x * v.x + v.y * v.y + v.z * v.z + v.w * v.w;
        }
        hs2g[tid] = -0.5f * a;
    }
    if (tid < CC * 1024) {
        // B-operand frag order: chunk ((c*8+nt)*2+sc)*64+lane holds
        // shp[c][nt*16+(lane&15)][sc*32+(lane>>4)*8 + j], j=0..7 (RNE bf16)
        int c   = tid >> 10;
        int r   = tid & 1023;
        int nt  = r >> 7;
        int scb = (r >> 6) & 1;
        int l   = r & 63;
        int row  = nt * 16 + (l & 15);
        int koff = scb * 32 + (l >> 4) * 8;
        const float* s = shp + ((size_t)(c * KK + row)) * SS + koff;
        float4 f0 = *(const float4*)s;
        float4 f1 = *(const float4*)(s + 4);
        uint4 o;
        o.x = (bf16_rne(f0.y) << 16) | bf16_rne(f0.x);
        o.y = (bf16_rne(f0.w) << 16) | bf16_rne(f0.z);
        o.z = (bf16_rne(f1.y) << 16) | bf16_rne(f1.x);
        o.w = (bf16_rne(f1.w) << 16) | bf16_rne(f1.z);
        shb[tid] = o;
    }
}

// ---------------------------------------------------------------------------
// Main: 512 blocks = (n, 512-window group). Round-2 structure and finish
// protocol (tripwire-validated twice, NO __threadfence -- the agent-scope
// fence compiles to a full per-XCD L2 writeback/invalidate; 512 blocks x 2
// fences cost ~60 us in round 6). Delta vs round 2: the x^2 prefix scan
// stays in registers and writes hx directly (no Ps buffer), cutting
// barriers to 1 per iteration; hx dual-buffered so no trailing barrier.
__global__ __launch_bounds__(256, 2) void me_main(
        const float* __restrict__ x,
        const ushort* __restrict__ shb_g,
        const float* __restrict__ hs2g,
        unsigned* __restrict__ d2g,
        unsigned* __restrict__ cnt,
        float* __restrict__ out) {

    __shared__ __align__(16) ushort shb[CC * 8192];   // 48 KB shapelet frags
    __shared__ __align__(8) ushort xs2[2][2][CC][320];// [buf][copy][c] bf16 x
    __shared__ __align__(16) float hx[2][CC][256];    // [buf] -0.5*sliding x2
    __shared__ unsigned red[KK];
    __shared__ int lastflag;

    const int b    = blockIdx.x;
    const int n    = b >> 3;          // BLKN=8 blocks per n
    const int tg   = b & 7;
    const int t    = threadIdx.x;
    const int lane = t & 63, wave = t >> 6;
    const int quad = lane >> 4, col = lane & 15;
    const int wbase = wave * 64;      // wave's window base within supertile

    if (t < KK) red[t] = 0x7F800000u;

    // ---- DMA all shapelet frags global(ws) -> LDS, once per block ----
    {
        typedef __attribute__((address_space(1))) const uint4 gu4;
        typedef __attribute__((address_space(3))) uint4 lu4;
        const uint4* gbase = (const uint4*)shb_g;
        #pragma unroll
        for (int it = 0; it < 12; ++it) {
            const uint4* gp = gbase + it * 256 + t;                 // per-lane
            uint4* lp = (uint4*)shb + (it * 256 + wave * 64);       // wave-uniform
            __builtin_amdgcn_global_load_lds((gu4*)gp, (lu4*)lp, 16, 0, 0);
        }
    }

    // ---- -0.5*s2 into registers (indexed by this lane's col) ----
    float hsv[CC][8];
    #pragma unroll
    for (int c = 0; c < CC; ++c)
        #pragma unroll
        for (int nt = 0; nt < 8; ++nt)
            hsv[c][nt] = hs2g[c * KK + nt * 16 + col];

    const float* xb = x + (size_t)n * (CC * LL);

    float rmax[8];
    #pragma unroll
    for (int nt = 0; nt < 8; ++nt) rmax[nt] = -3.4e38f;

    for (int it = 0; it < 2; ++it) {
        const int buf = it;
        const int w0  = tg * 512 + it * 256;

        // ---- stage 256+63 x elems per channel, bf16 dual-copy ----
        if (t < 240) {
            int c = t / 80, q = t - c * 80;
            int idx = q * 4, gi = w0 + idx;
            float4 v;
            if (gi + 3 < LL) v = *(const float4*)(xb + c * LL + gi);
            else {
                v.x = (gi     < LL) ? xb[c * LL + gi]     : 0.f;
                v.y = (gi + 1 < LL) ? xb[c * LL + gi + 1] : 0.f;
                v.z = (gi + 2 < LL) ? xb[c * LL + gi + 2] : 0.f;
                v.w = (gi + 3 < LL) ? xb[c * LL + gi + 3] : 0.f;
            }
            unsigned h0 = bf16_rne(v.x), h1 = bf16_rne(v.y);
            unsigned h2 = bf16_rne(v.z), h3 = bf16_rne(v.w);
            uint2 p0; p0.x = h0 | (h1 << 16); p0.y = h2 | (h3 << 16);
            *(uint2*)&xs2[buf][0][c][idx] = p0;                 // copy0: x[i]
            if (idx > 0) xs2[buf][1][c][idx - 1] = (ushort)h0;  // copy1: x[i+1]
            *(uint*)&xs2[buf][1][c][idx] = h1 | (h2 << 16);
            xs2[buf][1][c][idx + 2] = (ushort)h3;
        }
        // ---- in-register x^2 prefix scan -> hx, 1 wave per channel ----
        if (wave < CC) {
            const float* xp = xb + wave * LL + w0;
            float p[5]; float runv = 0.f;
            #pragma unroll
            for (int i = 0; i < 5; ++i) {
                int idx = lane * 5 + i;
                float v = (w0 + idx < LL) ? xp[idx] : 0.f;
                runv += v * v; p[i] = runv;
            }
            float scv = runv;
            #pragma unroll
            for (int d = 1; d < 64; d <<= 1) {
                float u = __shfl_up(scv, d, 64);
                if (lane >= d) scv += u;
            }
            float excl = scv - runv;
            #pragma unroll
            for (int i = 0; i < 5; ++i) p[i] += excl;
            // hx[w] = -0.5*(P[w+63]-P[w-1]); w = 5*lane+i
            // P[w+63]: i<2 -> lane+12 elem i+3; i>=2 -> lane+13 elem i-2
            float hi0 = __shfl_down(p[3], 12, 64);
            float hi1 = __shfl_down(p[4], 12, 64);
            float hi2 = __shfl_down(p[0], 13, 64);
            float hi3 = __shfl_down(p[1], 13, 64);
            float hi4 = __shfl_down(p[2], 13, 64);
            float up4 = __shfl_up(p[4], 1, 64);
            float hi[5] = {hi0, hi1, hi2, hi3, hi4};
            float lo[5];
            lo[0] = (lane == 0) ? 0.f : up4;
            lo[1] = p[0]; lo[2] = p[1]; lo[3] = p[2]; lo[4] = p[3];
            int wb = lane * 5;
            if (wb < 256) {                       // lanes 0..51
                #pragma unroll
                for (int i = 0; i < 5; ++i) {
                    int w = wb + i;
                    if (w < 256) {
                        float o = -0.5f * (hi[i] - lo[i]);
                        if (w0 + w >= WW) o = -1e30f;   // pad windows masked
                        hx[buf][wave][w] = o;
                    }
                }
            }
        }
        __syncthreads();   // one barrier per iteration (covers DMA on it==0)

        #pragma unroll
        for (int c = 0; c < CC; ++c) {
            // -0.5*x2 for this wave's 64 window rows (LDS, quad-broadcast)
            v4f hxv[4];
            #pragma unroll
            for (int mt = 0; mt < 4; ++mt)
                hxv[mt] = *(const v4f*)&hx[buf][c][wbase + mt * 16 + quad * 4];
            // A-frags: 4 m-tiles x 2 k-chunks, dual-copy dword-aligned reads
            v8s af[4][2];
            #pragma unroll
            for (int mt = 0; mt < 4; ++mt)
                #pragma unroll
                for (int sc = 0; sc < 2; ++sc) {
                    int e0 = wbase + mt * 16 + col + sc * 32 + quad * 8;
                    int p  = col & 1;
                    const uint* ap = (const uint*)&xs2[buf][p][c][e0 - p];
                    union { v8s v; uint u[4]; } au;
                    au.u[0] = ap[0]; au.u[1] = ap[1];
                    au.u[2] = ap[2]; au.u[3] = ap[3];
                    af[mt][sc] = au.v;
                }
            // two groups of 4 n-tiles to bound acc register pressure
            #pragma unroll
            for (int g = 0; g < 2; ++g) {
                v4f acc[4][4];   // [nt2][mt]
                #pragma unroll
                for (int nt2 = 0; nt2 < 4; ++nt2) {
                    float h = hsv[c][g * 4 + nt2];
                    v4f a = {h, h, h, h};
                    #pragma unroll
                    for (int mt = 0; mt < 4; ++mt) acc[nt2][mt] = a;
                }
                #pragma unroll
                for (int sc = 0; sc < 2; ++sc)
                    #pragma unroll
                    for (int nt2 = 0; nt2 < 4; ++nt2) {
                        int nt = g * 4 + nt2;
                        v8s bfr = *(const v8s*)(shb + (((c * 8 + nt) * 2 + sc) * 64 + lane) * 8);
                        #pragma unroll
                        for (int mt = 0; mt < 4; ++mt)
                            acc[nt2][mt] = __builtin_amdgcn_mfma_f32_16x16x32_bf16(
                                af[mt][sc], bfr, acc[nt2][mt], 0, 0, 0);
                    }
                // epilogue: add -0.5*x2 rows, fold max over 16 window rows
                #pragma unroll
                for (int nt2 = 0; nt2 < 4; ++nt2) {
                    float m = -3.4e38f;
                    #pragma unroll
                    for (int mt = 0; mt < 4; ++mt) {
                        v4f a = acc[nt2][mt];
                        #pragma unroll
                        for (int r = 0; r < 4; ++r)
                            m = fmaxf(m, a[r] + hxv[mt][r]);
                    }
                    rmax[g * 4 + nt2] = fmaxf(rmax[g * 4 + nt2], m);
                }
            }
        }
        // no trailing barrier: next iteration writes the other xs2/hx buffer;
        // all threads passed this iteration's barrier before any writer
        // touches buf^1, and compute reads only buf
    }

    // ---- reduce over quads (window rows live across quad+regs) ----
    #pragma unroll
    for (int nt = 0; nt < 8; ++nt) {
        float v = rmax[nt];
        v = fmaxf(v, __shfl_xor(v, 16, 64));
        v = fmaxf(v, __shfl_xor(v, 32, 64));
        rmax[nt] = v;
    }
    if (quad == 0) {
        #pragma unroll
        for (int nt = 0; nt < 8; ++nt) {
            float d2 = fmaxf(-2.f * rmax[nt], 0.f);
            atomicMin(&red[nt * 16 + col], __float_as_uint(d2));
        }
    }
    __syncthreads();
    if (t < KK) atomicMin(&d2g[n * KK + t], red[t]);   // device-scope RMW

    // ---- last block for this n writes sqrt -> out (round-2 protocol) ----
    __syncthreads();   // vmcnt(0) drain: d2g mins globally done before cnt
    if (t == 0) {
        unsigned old = atomicAdd(&cnt[n], 1u);
        lastflag = (old == BLKN - 1) ? 1 : 0;
    }
    __syncthreads();
    if (lastflag && t < KK) {
        unsigned bits = atomicMin(&d2g[n * KK + t], 0x7F800000u);
        out[n * KK + t] = sqrtf(__uint_as_float(bits));
    }
}

// ---------------------------------------------------------------------------
extern "C" void kernel_launch(void* const* d_in, const int* in_sizes, int n_in,
                              void* d_out, int out_size, void* d_ws, size_t ws_size,
                              hipStream_t stream) {
    const float* x   = (const float*)d_in[0];   // (N, C, L) fp32
    const float* shp = (const float*)d_in[1];   // (C, K, S) fp32
    unsigned* d2g  = (unsigned*)d_ws;
    unsigned* cnt  = (unsigned*)((char*)d_ws + WS_CNT_OFF);
    float*    hs2g = (float*)((char*)d_ws + WS_HS2_OFF);
    uint4*    shb  = (uint4*)((char*)d_ws + WS_SHB_OFF);
    float* out = (float*)d_out;

    hipLaunchKernelGGL(me_prep, dim3(32), dim3(256), 0, stream,
                       shp, d2g, cnt, hs2g, shb);
    hipLaunchKernelGGL(me_main, dim3(NN * BLKN), dim3(256), 0, stream,
                       x, (const ushort*)shb, hs2g, d2g, cnt, out);
}